// Round 6
// baseline (405.652 us; speedup 1.0000x reference)
//
#include <hip/hip_runtime.h>
#include <math.h>

// Problem constants (from reference)
#define B_ 16
#define P_ 131072
#define G_ 32
constexpr float OVER_THR = 0.35f;
constexpr float VAR0 = 0.1f;
constexpr float VAR1 = 0.2f;
constexpr int NEG_POS = 7;
constexpr int UNR = 4;                   // priors per thread in k_match
constexpr int LOSS_X = P_ / 256;         // 512 blocks per image in k_loss
constexpr int LOSS_BLOCKS = LOSS_X * B_; // 8192 partials
constexpr int NB1 = 4096;                // level 1: float bits 31..20
constexpr int NB2 = 256;                 // level 2: bits 19..12
constexpr int NB3 = 4096;                // level 3: bits 11..0
constexpr int SCAN_BLKS = 16;            // blocks per image in mining scans

// ---------------- helpers ----------------
__device__ inline float s1(float d) {            // smooth L1
    d = fabsf(d);
    return d < 1.f ? 0.5f * d * d : d - 0.5f;
}

__device__ inline unsigned long long shfl_xor_u64(unsigned long long x, int m) {
    unsigned lo = (unsigned)x, hi = (unsigned)(x >> 32);
    lo = __shfl_xor(lo, m);
    hi = __shfl_xor(hi, m);
    return ((unsigned long long)hi << 32) | lo;
}

// xor-butterfly step within 32-lane groups, no index math (BitMode swizzle)
template <int IMM>
__device__ inline unsigned long long swz64(unsigned long long x) {
    unsigned lo = (unsigned)__builtin_amdgcn_ds_swizzle((int)(unsigned)x, IMM);
    unsigned hi = (unsigned)__builtin_amdgcn_ds_swizzle((int)(unsigned)(x >> 32), IMM);
    return ((unsigned long long)hi << 32) | lo;
}

// Block-parallel (1024 thr) top-k bin select over NB global bins.
// Writes *sbin / *srem (rem within bin) from the unique crossing thread.
template <int NB>
__device__ void blk_select(const unsigned* __restrict__ gc, unsigned rem,
                           int* sbin, unsigned* srem) {
    constexpr int CHUNK = (NB + 1023) / 1024;
    const int tid = threadIdx.x;
    unsigned cnt[CHUNK];
    unsigned csum = 0;
#pragma unroll
    for (int j = 0; j < CHUNK; ++j) {
        int idx = tid * CHUNK + j;
        unsigned c = (idx < NB) ? gc[idx] : 0u;
        cnt[j] = c; csum += c;
    }
    __shared__ unsigned ss[1024];
    ss[tid] = csum;
    __syncthreads();
    for (int off = 1; off < 1024; off <<= 1) {       // suffix scan (desc bins)
        unsigned o = (tid + off < 1024) ? ss[tid + off] : 0u;
        __syncthreads();
        ss[tid] += o;
        __syncthreads();
    }
    unsigned incl = ss[tid], excl = incl - csum;
    if (excl < rem && incl >= rem) {
        unsigned r = rem - excl, cum = 0;
        int sb_ = tid * CHUNK;
#pragma unroll
        for (int j = CHUNK - 1; j >= 0; --j) {
            unsigned c = cnt[j];
            if (cum + c >= r) { sb_ = tid * CHUNK + j; r -= cum; break; }
            cum += c;
        }
        *sbin = sb_; *srem = r;
    }
    __syncthreads();
}

// Sum (double) of gs[bin+1..NB); valid on tid==0 only.
template <int NB>
__device__ double blk_sum_above(const float* __restrict__ gs, int bin) {
    const int tid = threadIdx.x;
    double a = 0;
    for (int i = bin + 1 + tid; i < NB; i += 1024) a += (double)gs[i];
#pragma unroll
    for (int off = 32; off > 0; off >>= 1) a += __shfl_xor(a, off);
    __shared__ double rs[16];
    int lane = tid & 63, wave = tid >> 6;
    if (lane == 0) rs[wave] = a;
    __syncthreads();
    double t = 0;
    if (tid == 0) for (int w = 0; w < 16; ++w) t += rs[w];
    return t;
}

// ---------------- kernels ----------------
// Per (b,prior): best truth -> bt_ov/bt_idx. Per (b,truth): best prior via
// packed (iou<<32)|~p atomicMax. UNR=4 -> 2048 blocks (8/CU, full occupancy);
// one pack+butterfly per g (not per pair); ds_swizzle butterfly.
__global__ __launch_bounds__(256, 3) void k_match(
        const float4* __restrict__ priors4, const float* __restrict__ targets,
        float* __restrict__ bt_ov, unsigned char* __restrict__ bt_idx,
        unsigned long long* __restrict__ pack) {
    const int b = blockIdx.y;
    const int base = blockIdx.x * (256 * UNR);
    const int tid = threadIdx.x;
    __shared__ float4 tb4[G_];
    __shared__ float tA[G_];
    __shared__ unsigned long long red[G_][4];
    if (tid < G_) {
        const float* tp = targets + ((size_t)b * G_ + tid) * 15;
        float x1 = tp[0], y1 = tp[1], x2 = tp[2], y2 = tp[3];
        tb4[tid] = make_float4(x1, y1, x2, y2);
        tA[tid] = (x2 - x1) * (y2 - y1);
    }
    __syncthreads();

    float px1[UNR], py1[UNR], px2[UNR], py2[UNR], pap[UNR], best[UNR];
    int bidx[UNR];
#pragma unroll
    for (int j = 0; j < UNR; ++j) {
        float4 pr = priors4[base + j * 256 + tid];
        px1[j] = pr.x - pr.z * 0.5f;  py1[j] = pr.y - pr.w * 0.5f;
        px2[j] = pr.x + pr.z * 0.5f;  py2[j] = pr.y + pr.w * 0.5f;
        pap[j] = pr.z * pr.w;
        best[j] = -1.0f; bidx[j] = 0;
    }
    const int lane = tid & 63, wave = tid >> 6;
#pragma unroll 2
    for (int g = 0; g < G_; ++g) {
        float4 t = tb4[g];
        float ta = tA[g];
        float gb = -1.0f; int gj = 0;
#pragma unroll
        for (int j = 0; j < UNR; ++j) {
            float iw = fminf(t.z, px2[j]) - fmaxf(t.x, px1[j]);
            float ih = fminf(t.w, py2[j]) - fmaxf(t.y, py1[j]);
            float inter = fmaxf(iw, 0.f) * fmaxf(ih, 0.f);
            float iou = inter * __builtin_amdgcn_rcpf(ta + pap[j] - inter);
            if (iou > best[j]) { best[j] = iou; bidx[j] = g; }  // first-wins
            if (iou > gb) { gb = iou; gj = j; }                 // lowest p wins
        }
        unsigned p = (unsigned)(base + (gj << 8) + tid);
        unsigned long long pk =
            ((unsigned long long)__float_as_uint(gb) << 32) | (unsigned)(~p);
        unsigned long long o;
        o = shfl_xor_u64(pk, 32);  if (o > pk) pk = o;
        o = swz64<0x401F>(pk);     if (o > pk) pk = o;
        o = swz64<0x201F>(pk);     if (o > pk) pk = o;
        o = swz64<0x101F>(pk);     if (o > pk) pk = o;
        o = swz64<0x081F>(pk);     if (o > pk) pk = o;
        o = swz64<0x041F>(pk);     if (o > pk) pk = o;
        if (lane == 0) red[g][wave] = pk;
    }
    __syncthreads();
    if (tid < G_) {
        unsigned long long m = red[tid][0];
#pragma unroll
        for (int w = 1; w < 4; ++w) if (red[tid][w] > m) m = red[tid][w];
        atomicMax(&pack[b * G_ + tid], m);
    }
#pragma unroll
    for (int j = 0; j < UNR; ++j) {
        int p = base + j * 256 + tid;
        size_t o = (size_t)b * P_ + p;
        bt_ov[o] = best[j];
        bt_idx[o] = (unsigned char)bidx[j];
    }
}

// Per prior: CE; positives: smooth-L1 on encoded loc/landm. Override fused:
// compare p against the 32 packed best-prior winners (ascending g = last-wins).
__global__ __launch_bounds__(256) void k_loss(
        const float2* __restrict__ conf2, const float4* __restrict__ loc4,
        const float* __restrict__ landm, const float4* __restrict__ priors4,
        const float* __restrict__ targets, const unsigned long long* __restrict__ pack,
        const float* __restrict__ bt_ov, const unsigned char* __restrict__ bt_idx,
        float* __restrict__ ce_neg,
        double* __restrict__ pb, double* __restrict__ pl,
        double* __restrict__ pc, int* __restrict__ npos) {
    const int b = blockIdx.y;
    const int p = blockIdx.x * 256 + threadIdx.x;
    const int tid = threadIdx.x;
    __shared__ float tg[G_ * 15];
    __shared__ unsigned ptg[G_];
    for (int i = tid; i < G_ * 15; i += 256) tg[i] = targets[(size_t)b * G_ * 15 + i];
    if (tid < G_) ptg[tid] = ~(unsigned)(pack[b * G_ + tid] & 0xFFFFFFFFull);
    __syncthreads();

    const size_t gp = (size_t)b * P_ + p;
    float ov = bt_ov[gp];
    int ti = bt_idx[gp];
#pragma unroll
    for (int g = 0; g < G_; ++g)
        if ((unsigned)p == ptg[g]) { ov = 2.0f; ti = g; }   // last-g-wins
    const float* t = &tg[ti * 15];
    float label = t[14];
    int conf_t = (ov < OVER_THR) ? 0 : (int)label;
    bool pos = conf_t > 0;
    int cls = conf_t > 0 ? conf_t : 0;

    float2 c2 = conf2[gp];
    float mx = fmaxf(c2.x, c2.y);
    float lse = mx + logf(expf(c2.x - mx) + expf(c2.y - mx));
    float ce = lse - (cls ? c2.y : c2.x);
    ce_neg[gp] = (!pos && conf_t >= 0) ? ce : 0.f;

    float lb = 0.f, ll = 0.f;
    if (pos) {
        float4 pr = priors4[p];
        float vx = VAR0 * pr.z, vy = VAR0 * pr.w;
        float g0 = ((t[0] + t[2]) * 0.5f - pr.x) / vx;
        float g1 = ((t[1] + t[3]) * 0.5f - pr.y) / vy;
        float g2 = logf((t[2] - t[0]) / pr.z) / VAR1;
        float g3 = logf((t[3] - t[1]) / pr.w) / VAR1;
        float4 ld = loc4[gp];
        lb = s1(ld.x - g0) + s1(ld.y - g1) + s1(ld.z - g2) + s1(ld.w - g3);
        const float* lmp = landm + gp * 10;
#pragma unroll
        for (int i = 0; i < 5; ++i) {
            float2 lm = *(const float2*)(lmp + 2 * i);
            ll += s1(lm.x - (t[4 + 2 * i] - pr.x) / vx)
                + s1(lm.y - (t[5 + 2 * i] - pr.y) / vy);
        }
    }
    double vb = lb, vl = ll, vc = pos ? (double)ce : 0.0;
    int vp = pos ? 1 : 0;
#pragma unroll
    for (int off = 32; off > 0; off >>= 1) {
        vb += __shfl_xor(vb, off);
        vl += __shfl_xor(vl, off);
        vc += __shfl_xor(vc, off);
        vp += __shfl_xor(vp, off);
    }
    __shared__ double rb[4], rl[4], rc[4];
    __shared__ int rp[4];
    int lane = tid & 63, wave = tid >> 6;
    if (lane == 0) { rb[wave] = vb; rl[wave] = vl; rc[wave] = vc; rp[wave] = vp; }
    __syncthreads();
    if (tid == 0) {
        double sb = 0, sl = 0, sc = 0; int sp = 0;
        for (int w = 0; w < 4; ++w) { sb += rb[w]; sl += rl[w]; sc += rc[w]; sp += rp[w]; }
        int bi = blockIdx.y * LOSS_X + blockIdx.x;
        pb[bi] = sb; pl[bi] = sl; pc[bi] = sc;
        if (sp) atomicAdd(&npos[b], sp);
    }
}

// Mining L1: 12-bit cnt+sum histogram; last block (ticket) reduces the image's
// loss partials -> imgsum, selects bin, adds sum-above to tot[2].
__global__ __launch_bounds__(1024) void k_ms1(
        const float* __restrict__ ce_neg, const double* __restrict__ pb,
        const double* __restrict__ pl, const double* __restrict__ pc,
        const int* __restrict__ npos, unsigned* __restrict__ gcnt,
        float* __restrict__ gsum, int* __restrict__ sel, unsigned* __restrict__ remk,
        int* __restrict__ tick, double* __restrict__ imgsum, double* __restrict__ tot) {
    const int b = blockIdx.y;
    const int tid = threadIdx.x;
    __shared__ unsigned hc[NB1];
    __shared__ float hs[NB1];
    for (int i = tid; i < NB1; i += 1024) { hc[i] = 0; hs[i] = 0.f; }
    __syncthreads();
    const float4* v4 = (const float4*)(ce_neg + (size_t)b * P_);
    const int c4 = P_ / SCAN_BLKS / 4;
    const int s4 = blockIdx.x * c4;
    for (int i = s4 + tid; i < s4 + c4; i += 1024) {
        float4 x = v4[i];
        unsigned u0 = __float_as_uint(x.x), u1 = __float_as_uint(x.y);
        unsigned u2 = __float_as_uint(x.z), u3 = __float_as_uint(x.w);
        atomicAdd(&hc[u0 >> 20], 1u); atomicAdd(&hs[u0 >> 20], x.x);
        atomicAdd(&hc[u1 >> 20], 1u); atomicAdd(&hs[u1 >> 20], x.y);
        atomicAdd(&hc[u2 >> 20], 1u); atomicAdd(&hs[u2 >> 20], x.z);
        atomicAdd(&hc[u3 >> 20], 1u); atomicAdd(&hs[u3 >> 20], x.w);
    }
    __syncthreads();
    unsigned* gc = gcnt + b * NB1;
    float* gs = gsum + b * NB1;
    for (int i = tid; i < NB1; i += 1024)
        if (hc[i]) { atomicAdd(&gc[i], hc[i]); atomicAdd(&gs[i], hs[i]); }
    __threadfence();
    __shared__ int amLast;
    if (tid == 0) amLast = (atomicAdd(&tick[b], 1) == SCAN_BLKS - 1);
    __syncthreads();
    if (!amLast) return;
    __threadfence();
    // reduce this image's loss partials (always, even if k<=0)
    double sb = 0, sl = 0, sc = 0;
    for (int i = tid; i < LOSS_X; i += 1024) {
        sb += pb[b * LOSS_X + i]; sl += pl[b * LOSS_X + i]; sc += pc[b * LOSS_X + i];
    }
#pragma unroll
    for (int off = 32; off > 0; off >>= 1) {
        sb += __shfl_xor(sb, off); sl += __shfl_xor(sl, off); sc += __shfl_xor(sc, off);
    }
    __shared__ double r3[16][3];
    int lane = tid & 63, wave = tid >> 6;
    if (lane == 0) { r3[wave][0] = sb; r3[wave][1] = sl; r3[wave][2] = sc; }
    __syncthreads();
    if (tid == 0) {
        double a = 0, c = 0, d = 0;
        for (int w = 0; w < 16; ++w) { a += r3[w][0]; c += r3[w][1]; d += r3[w][2]; }
        imgsum[b * 3 + 0] = a; imgsum[b * 3 + 1] = c; imgsum[b * 3 + 2] = d;
    }
    long long k = (long long)NEG_POS * npos[b];
    if (k > P_ - 1) k = P_ - 1;
    if (k <= 0) { if (tid == 0) sel[b] = -1; return; }
    __shared__ int sb_;
    __shared__ unsigned sr_;
    blk_select<NB1>(gc, (unsigned)k, &sb_, &sr_);
    double above = blk_sum_above<NB1>(gs, sb_);
    if (tid == 0) {
        atomicAdd(&tot[2], above);
        sel[b] = sb_; remk[b] = sr_;
    }
}

// Mining L2: 8-bit cnt+sum of elements in the selected L1 bin; last block
// selects, extends prefix, adds sum-above.
__global__ __launch_bounds__(1024) void k_ms2(
        const float* __restrict__ ce_neg, const int* __restrict__ sel,
        unsigned* __restrict__ gcnt, float* __restrict__ gsum,
        unsigned* __restrict__ pref, unsigned* __restrict__ remk,
        int* __restrict__ tick, double* __restrict__ tot) {
    const int b = blockIdx.y;
    const int s1v = sel[b];
    if (s1v < 0) return;
    const int tid = threadIdx.x;
    __shared__ unsigned hc[NB2];
    __shared__ float hs[NB2];
    if (tid < NB2) { hc[tid] = 0; hs[tid] = 0.f; }
    __syncthreads();
    const float4* v4 = (const float4*)(ce_neg + (size_t)b * P_);
    const int c4 = P_ / SCAN_BLKS / 4;
    const int s4 = blockIdx.x * c4;
    for (int i = s4 + tid; i < s4 + c4; i += 1024) {
        float4 x = v4[i];
        unsigned u0 = __float_as_uint(x.x), u1 = __float_as_uint(x.y);
        unsigned u2 = __float_as_uint(x.z), u3 = __float_as_uint(x.w);
        if ((int)(u0 >> 20) == s1v) { atomicAdd(&hc[(u0 >> 12) & 255u], 1u); atomicAdd(&hs[(u0 >> 12) & 255u], x.x); }
        if ((int)(u1 >> 20) == s1v) { atomicAdd(&hc[(u1 >> 12) & 255u], 1u); atomicAdd(&hs[(u1 >> 12) & 255u], x.y); }
        if ((int)(u2 >> 20) == s1v) { atomicAdd(&hc[(u2 >> 12) & 255u], 1u); atomicAdd(&hs[(u2 >> 12) & 255u], x.z); }
        if ((int)(u3 >> 20) == s1v) { atomicAdd(&hc[(u3 >> 12) & 255u], 1u); atomicAdd(&hs[(u3 >> 12) & 255u], x.w); }
    }
    __syncthreads();
    unsigned* gc = gcnt + b * NB2;
    float* gs = gsum + b * NB2;
    if (tid < NB2 && hc[tid]) { atomicAdd(&gc[tid], hc[tid]); atomicAdd(&gs[tid], hs[tid]); }
    __threadfence();
    __shared__ int amLast;
    if (tid == 0) amLast = (atomicAdd(&tick[b], 1) == SCAN_BLKS - 1);
    __syncthreads();
    if (!amLast) return;
    __threadfence();
    __shared__ int sb_;
    __shared__ unsigned sr_;
    blk_select<NB2>(gc, remk[b], &sb_, &sr_);
    double above = blk_sum_above<NB2>(gs, sb_);
    if (tid == 0) {
        atomicAdd(&tot[2], above);
        pref[b] = ((unsigned)s1v << 8) | (unsigned)sb_;   // 20-bit prefix
        remk[b] = sr_;
    }
}

// Mining L3: 12-bit cnt+sum of prefix-matching elements; last block selects the
// exact threshold and adds sum-above + ties (rem * T).
__global__ __launch_bounds__(1024) void k_ms3(
        const float* __restrict__ ce_neg, const int* __restrict__ sel,
        const unsigned* __restrict__ pref, const unsigned* __restrict__ remk,
        unsigned* __restrict__ gcnt, float* __restrict__ gsum,
        int* __restrict__ tick, double* __restrict__ tot) {
    const int b = blockIdx.y;
    if (sel[b] < 0) return;
    const unsigned pf = pref[b];
    const int tid = threadIdx.x;
    __shared__ unsigned hc[NB3];
    __shared__ float hs[NB3];
    for (int i = tid; i < NB3; i += 1024) { hc[i] = 0; hs[i] = 0.f; }
    __syncthreads();
    const float4* v4 = (const float4*)(ce_neg + (size_t)b * P_);
    const int c4 = P_ / SCAN_BLKS / 4;
    const int s4 = blockIdx.x * c4;
    for (int i = s4 + tid; i < s4 + c4; i += 1024) {
        float4 x = v4[i];
        unsigned u0 = __float_as_uint(x.x), u1 = __float_as_uint(x.y);
        unsigned u2 = __float_as_uint(x.z), u3 = __float_as_uint(x.w);
        if ((u0 >> 12) == pf) { atomicAdd(&hc[u0 & 4095u], 1u); atomicAdd(&hs[u0 & 4095u], x.x); }
        if ((u1 >> 12) == pf) { atomicAdd(&hc[u1 & 4095u], 1u); atomicAdd(&hs[u1 & 4095u], x.y); }
        if ((u2 >> 12) == pf) { atomicAdd(&hc[u2 & 4095u], 1u); atomicAdd(&hs[u2 & 4095u], x.z); }
        if ((u3 >> 12) == pf) { atomicAdd(&hc[u3 & 4095u], 1u); atomicAdd(&hs[u3 & 4095u], x.w); }
    }
    __syncthreads();
    unsigned* gc = gcnt + b * NB3;
    float* gs = gsum + b * NB3;
    for (int i = tid; i < NB3; i += 1024)
        if (hc[i]) { atomicAdd(&gc[i], hc[i]); atomicAdd(&gs[i], hs[i]); }
    __threadfence();
    __shared__ int amLast;
    if (tid == 0) amLast = (atomicAdd(&tick[b], 1) == SCAN_BLKS - 1);
    __syncthreads();
    if (!amLast) return;
    __threadfence();
    __shared__ int sb_;
    __shared__ unsigned sr_;
    blk_select<NB3>(gc, remk[b], &sb_, &sr_);
    double above = blk_sum_above<NB3>(gs, sb_);
    if (tid == 0) {
        unsigned T = (pf << 12) | (unsigned)sb_;
        atomicAdd(&tot[2], above + (double)sr_ * (double)__uint_as_float(T));
    }
}

// Final: combine per-image sums + mined CE, divide by total positives.
__global__ void k_final(const double* __restrict__ imgsum,
                        const int* __restrict__ npos,
                        const double* __restrict__ tot, float* __restrict__ out) {
    if (threadIdx.x == 0) {
        double sb = 0, sl = 0, sc = 0;
        long long tp = 0;
        for (int b = 0; b < B_; ++b) {
            sb += imgsum[b * 3 + 0];
            sl += imgsum[b * 3 + 1];
            sc += imgsum[b * 3 + 2];
            tp += npos[b];
        }
        double n = tp > 0 ? (double)tp : 1.0;
        out[0] = (float)(sb / n);             // loss_box
        out[1] = (float)((sc + tot[2]) / n);  // loss_c (pos part + mined negs)
        out[2] = (float)(sl / n);             // loss_landm
    }
}

// ---------------- launch ----------------
extern "C" void kernel_launch(void* const* d_in, const int* in_sizes, int n_in,
                              void* d_out, int out_size, void* d_ws, size_t ws_size,
                              hipStream_t stream) {
    const float* conf    = (const float*)d_in[0];
    const float* loc     = (const float*)d_in[1];
    const float* landm   = (const float*)d_in[2];
    const float* priors  = (const float*)d_in[3];
    const float* targets = (const float*)d_in[4];

    char* ws = (char*)d_ws;
    double* tot = (double*)ws;                                   // 4 doubles @0
    int* npos = (int*)(ws + 64);
    int* sel  = (int*)(ws + 128);
    unsigned* remk = (unsigned*)(ws + 192);
    unsigned* pref = (unsigned*)(ws + 256);
    int* tick1 = (int*)(ws + 320);
    int* tick2 = (int*)(ws + 384);
    int* tick3 = (int*)(ws + 448);
    unsigned long long* pack = (unsigned long long*)(ws + 512);  // 4 KB
    double* imgsum = (double*)(ws + 4608);                       // 48 doubles
    unsigned* gcnt1 = (unsigned*)(ws + 5120);                    // 256 KB
    float*    gsum1 = (float*)((char*)gcnt1 + (size_t)B_ * NB1 * 4);
    unsigned* gcnt2 = (unsigned*)((char*)gsum1 + (size_t)B_ * NB1 * 4);
    float*    gsum2 = (float*)((char*)gcnt2 + (size_t)B_ * NB2 * 4);
    unsigned* gcnt3 = (unsigned*)((char*)gsum2 + (size_t)B_ * NB2 * 4);
    float*    gsum3 = (float*)((char*)gcnt3 + (size_t)B_ * NB3 * 4);
    size_t zero_bytes = 5120 + (size_t)B_ * (NB1 * 2 + NB2 * 2 + NB3 * 2) * 4;
    size_t big = (zero_bytes + 255) & ~(size_t)255;
    size_t BP = (size_t)B_ * P_;
    float* bt_ov = (float*)(ws + big);
    unsigned char* bt_idx = (unsigned char*)(ws + big + BP * 4);
    float* ce_neg = (float*)(ws + big + BP * 5);
    char* part = ws + big + BP * 9;
    double* pb = (double*)part;
    double* pl = (double*)(part + LOSS_BLOCKS * 8);
    double* pc = (double*)(part + LOSS_BLOCKS * 16);

    // one memset zeroes all control scalars, pack, tickets, and histograms
    hipMemsetAsync(ws, 0, zero_bytes, stream);
    k_match<<<dim3(P_ / (256 * UNR), B_), 256, 0, stream>>>(
        (const float4*)priors, targets, bt_ov, bt_idx, pack);
    k_loss<<<dim3(LOSS_X, B_), 256, 0, stream>>>(
        (const float2*)conf, (const float4*)loc, landm, (const float4*)priors,
        targets, pack, bt_ov, bt_idx, ce_neg, pb, pl, pc, npos);
    k_ms1<<<dim3(SCAN_BLKS, B_), 1024, 0, stream>>>(
        ce_neg, pb, pl, pc, npos, gcnt1, gsum1, sel, remk, tick1, imgsum, tot);
    k_ms2<<<dim3(SCAN_BLKS, B_), 1024, 0, stream>>>(
        ce_neg, sel, gcnt2, gsum2, pref, remk, tick2, tot);
    k_ms3<<<dim3(SCAN_BLKS, B_), 1024, 0, stream>>>(
        ce_neg, sel, pref, remk, gcnt3, gsum3, tick3, tot);
    k_final<<<1, 64, 0, stream>>>(imgsum, npos, tot, (float*)d_out);
}

// Round 7
// 128.018 us; speedup vs baseline: 3.1687x; 3.1687x over previous
//
#include <hip/hip_runtime.h>
#include <math.h>

// Problem constants (from reference)
#define B_ 16
#define P_ 131072
#define G_ 32
constexpr float OVER_THR = 0.35f;
constexpr float VAR0 = 0.1f;
constexpr float VAR1 = 0.2f;
constexpr int NEG_POS = 7;
constexpr int UNR = 4;                         // priors per thread in k_match
constexpr int LOSS_X = P_ / 256;               // 512 blocks per image in k_loss
constexpr int LOSS_BLOCKS = LOSS_X * B_;       // 8192 partials
constexpr int NBIN13 = 8192;                   // 13-bit first-level histogram
constexpr int NBIN8 = 256;                     // second level (bits 18..11)
constexpr int NBIN11 = 2048;                   // third level (bits 10..0)
constexpr int SCAN_BLKS = 16;                  // blocks per image in scans

// ---------------- helpers ----------------
__device__ inline float s1(float d) {            // smooth L1
    d = fabsf(d);
    return d < 1.f ? 0.5f * d * d : d - 0.5f;
}

__device__ inline unsigned long long shfl_xor_u64(unsigned long long x, int m) {
    unsigned lo = (unsigned)x, hi = (unsigned)(x >> 32);
    lo = __shfl_xor(lo, m);
    hi = __shfl_xor(hi, m);
    return ((unsigned long long)hi << 32) | lo;
}

// Block-parallel top-k bin selection (256 threads).
template <int NB>
__device__ void topk_select(const unsigned* __restrict__ h, unsigned rem,
                            int* out_bin, unsigned* out_rem) {
    constexpr int CHUNK = NB / 256;
    const int tid = threadIdx.x;
    unsigned cnt[CHUNK];
    unsigned csum = 0;
#pragma unroll
    for (int j = 0; j < CHUNK; ++j) { cnt[j] = h[tid * CHUNK + j]; csum += cnt[j]; }
    __shared__ unsigned ss[256];
    ss[tid] = csum;
    __syncthreads();
    // Hillis-Steele suffix scan: ss[t] = sum over threads >= t (higher bins)
    for (int off = 1; off < 256; off <<= 1) {
        unsigned other = (tid + off < 256) ? ss[tid + off] : 0u;
        __syncthreads();
        ss[tid] += other;
        __syncthreads();
    }
    unsigned incl = ss[tid];
    unsigned excl = incl - csum;               // strictly above this chunk
    if (excl < rem && incl >= rem) {           // crossing chunk (unique)
        unsigned r = rem - excl, cum = 0;
        int selbin = tid * CHUNK;
#pragma unroll
        for (int j = CHUNK - 1; j >= 0; --j) {
            unsigned c = cnt[j];
            if (cum + c >= r) { selbin = tid * CHUNK + j; r = r - cum; break; }
            cum += c;
        }
        *out_bin = selbin;
        *out_rem = r;
    }
}

// ---------------- kernels ----------------
// Per (b,prior): best truth (first-wins ties) -> bt_ov/bt_idx. Per (b,truth):
// best prior via packed (iou<<32)|~p atomicMax. UNR=4 -> 2048 blocks (8/CU,
// removes round-5's grid-capped 23% occupancy); per-g float best tracking,
// single u64 pack + butterfly per g.
__global__ __launch_bounds__(256, 3) void k_match(
        const float4* __restrict__ priors4, const float* __restrict__ targets,
        float* __restrict__ bt_ov, unsigned char* __restrict__ bt_idx,
        unsigned long long* __restrict__ pack) {
    const int b = blockIdx.y;
    const int base = blockIdx.x * (256 * UNR);
    const int tid = threadIdx.x;
    __shared__ float tb[G_][5];                 // x1 y1 x2 y2 area
    __shared__ unsigned long long red[G_][4];
    if (tid < G_ * 4) {
        int g = tid >> 2, j = tid & 3;
        tb[g][j] = targets[((size_t)b * G_ + g) * 15 + j];
    }
    __syncthreads();
    if (tid < G_) tb[tid][4] = (tb[tid][2] - tb[tid][0]) * (tb[tid][3] - tb[tid][1]);
    __syncthreads();

    float px1[UNR], py1[UNR], px2[UNR], py2[UNR], pap[UNR], best[UNR];
    int bidx[UNR];
#pragma unroll
    for (int j = 0; j < UNR; ++j) {
        float4 pr = priors4[base + j * 256 + tid];
        px1[j] = pr.x - pr.z * 0.5f;  py1[j] = pr.y - pr.w * 0.5f;
        px2[j] = pr.x + pr.z * 0.5f;  py2[j] = pr.y + pr.w * 0.5f;
        pap[j] = pr.z * pr.w;
        best[j] = -1.0f; bidx[j] = 0;
    }
    const int lane = tid & 63, wave = tid >> 6;
#pragma unroll 2
    for (int g = 0; g < G_; ++g) {
        float t0 = tb[g][0], t1 = tb[g][1], t2 = tb[g][2], t3 = tb[g][3], ta = tb[g][4];
        float gb = -1.0f; int gj = 0;
#pragma unroll
        for (int j = 0; j < UNR; ++j) {
            float iw = fminf(t2, px2[j]) - fmaxf(t0, px1[j]);
            float ih = fminf(t3, py2[j]) - fmaxf(t1, py1[j]);
            float inter = fmaxf(iw, 0.f) * fmaxf(ih, 0.f);
            float iou = inter * __builtin_amdgcn_rcpf(ta + pap[j] - inter);
            if (iou > best[j]) { best[j] = iou; bidx[j] = g; }  // first-wins ties
            if (iou > gb) { gb = iou; gj = j; }   // first-j wins = lowest p
        }
        // single packed candidate per g: (iou_bits<<32) | ~p  (lowest p on ties)
        unsigned p = (unsigned)(base + (gj << 8) + tid);
        unsigned long long pk =
            ((unsigned long long)__float_as_uint(gb) << 32) | (unsigned)(~p);
#pragma unroll
        for (int off = 32; off > 0; off >>= 1) {
            unsigned long long o = shfl_xor_u64(pk, off);
            if (o > pk) pk = o;
        }
        if (lane == 0) red[g][wave] = pk;
    }
    __syncthreads();
    if (tid < G_) {
        unsigned long long m = red[tid][0];
#pragma unroll
        for (int w = 1; w < 4; ++w) if (red[tid][w] > m) m = red[tid][w];
        atomicMax(&pack[b * G_ + tid], m);
    }
#pragma unroll
    for (int j = 0; j < UNR; ++j) {
        int p = base + j * 256 + tid;
        size_t o = (size_t)b * P_ + p;
        bt_ov[o] = best[j];
        bt_idx[o] = (unsigned char)bidx[j];
    }
}

// Sequential per image: scatter with last-g-wins (numpy semantics).
__global__ void k_override(const unsigned long long* __restrict__ pack,
                           float* __restrict__ bt_ov, unsigned char* __restrict__ bt_idx) {
    int b = threadIdx.x;
    if (b >= B_) return;
    for (int g = 0; g < G_; ++g) {
        unsigned long long pk = pack[b * G_ + g];
        unsigned p = ~(unsigned)(pk & 0xFFFFFFFFull);
        if (p < P_) {
            bt_ov[(size_t)b * P_ + p] = 2.0f;
            bt_idx[(size_t)b * P_ + p] = (unsigned char)g;
        }
    }
}

// Per prior: CE; positives: smooth-L1 on encoded loc/landm. Partials per block.
__global__ __launch_bounds__(256) void k_loss(
        const float2* __restrict__ conf2, const float4* __restrict__ loc4,
        const float* __restrict__ landm, const float4* __restrict__ priors4,
        const float* __restrict__ targets,
        const float* __restrict__ bt_ov, const unsigned char* __restrict__ bt_idx,
        float* __restrict__ ce_neg,
        double* __restrict__ pb, double* __restrict__ pl,
        double* __restrict__ pc, int* __restrict__ pn) {
    const int b = blockIdx.y;
    const int p = blockIdx.x * 256 + threadIdx.x;
    const int tid = threadIdx.x;
    __shared__ float tg[G_ * 15];
    for (int i = tid; i < G_ * 15; i += 256) tg[i] = targets[(size_t)b * G_ * 15 + i];
    __syncthreads();

    const size_t gp = (size_t)b * P_ + p;
    float ov = bt_ov[gp];
    int ti = bt_idx[gp];
    const float* t = &tg[ti * 15];
    float label = t[14];
    int conf_t = (ov < OVER_THR) ? 0 : (int)label;
    bool pos = conf_t > 0;
    int cls = conf_t > 0 ? conf_t : 0;

    float2 c2 = conf2[gp];
    float mx = fmaxf(c2.x, c2.y);
    float lse = mx + logf(expf(c2.x - mx) + expf(c2.y - mx));
    float ce = lse - (cls ? c2.y : c2.x);
    ce_neg[gp] = (!pos && conf_t >= 0) ? ce : 0.f;

    float lb = 0.f, ll = 0.f;
    if (pos) {
        float4 pr = priors4[p];
        float vx = VAR0 * pr.z, vy = VAR0 * pr.w;
        float g0 = ((t[0] + t[2]) * 0.5f - pr.x) / vx;
        float g1 = ((t[1] + t[3]) * 0.5f - pr.y) / vy;
        float g2 = logf((t[2] - t[0]) / pr.z) / VAR1;
        float g3 = logf((t[3] - t[1]) / pr.w) / VAR1;
        float4 ld = loc4[gp];
        lb = s1(ld.x - g0) + s1(ld.y - g1) + s1(ld.z - g2) + s1(ld.w - g3);
        const float* lmp = landm + gp * 10;
#pragma unroll
        for (int i = 0; i < 5; ++i) {
            float2 lm = *(const float2*)(lmp + 2 * i);
            ll += s1(lm.x - (t[4 + 2 * i] - pr.x) / vx)
                + s1(lm.y - (t[5 + 2 * i] - pr.y) / vy);
        }
    }
    double vb = lb, vl = ll, vc = pos ? (double)ce : 0.0;
    int vp = pos ? 1 : 0;
#pragma unroll
    for (int off = 32; off > 0; off >>= 1) {
        vb += __shfl_xor(vb, off);
        vl += __shfl_xor(vl, off);
        vc += __shfl_xor(vc, off);
        vp += __shfl_xor(vp, off);
    }
    __shared__ double rb[4], rl[4], rc[4];
    __shared__ int rp[4];
    int lane = tid & 63, wave = tid >> 6;
    if (lane == 0) { rb[wave] = vb; rl[wave] = vl; rc[wave] = vc; rp[wave] = vp; }
    __syncthreads();
    if (tid == 0) {
        double sb = 0, sl = 0, sc = 0; int sp = 0;
        for (int w = 0; w < 4; ++w) { sb += rb[w]; sl += rl[w]; sc += rc[w]; sp += rp[w]; }
        int bi = blockIdx.y * LOSS_X + blockIdx.x;
        pb[bi] = sb; pl[bi] = sl; pc[bi] = sc; pn[bi] = sp;
    }
}

// Scan 1: 13-bit count histogram of ce_neg float bits, per image. float4 loads.
__global__ __launch_bounds__(1024) void k_hist13(
        const float* __restrict__ ce_neg, unsigned* __restrict__ hist) {
    const int b = blockIdx.y;
    const int tid = threadIdx.x;
    __shared__ unsigned h[NBIN13];
    for (int i = tid; i < NBIN13; i += 1024) h[i] = 0;
    __syncthreads();
    const float4* v4 = (const float4*)(ce_neg + (size_t)b * P_);
    const int c4 = P_ / SCAN_BLKS / 4;
    const int s4 = blockIdx.x * c4;
    for (int i = s4 + tid; i < s4 + c4; i += 1024) {
        float4 x = v4[i];
        atomicAdd(&h[__float_as_uint(x.x) >> 19], 1u);
        atomicAdd(&h[__float_as_uint(x.y) >> 19], 1u);
        atomicAdd(&h[__float_as_uint(x.z) >> 19], 1u);
        atomicAdd(&h[__float_as_uint(x.w) >> 19], 1u);
    }
    __syncthreads();
    unsigned* gh = hist + b * NBIN13;
    for (int i = tid; i < NBIN13; i += 1024)
        if (h[i]) atomicAdd(&gh[i], h[i]);
}

// Per image: sum num_pos from k_loss partials; parallel 13-bit select.
__global__ __launch_bounds__(256) void k_sel13(
        const unsigned* __restrict__ hist, const int* __restrict__ pn,
        int* __restrict__ sel, int* __restrict__ remk, int* __restrict__ npos) {
    const int b = blockIdx.x;
    const int tid = threadIdx.x;
    __shared__ int s_np;
    __shared__ int rnp[4];
    int loc = 0;
    for (int i = tid; i < LOSS_X; i += 256) loc += pn[b * LOSS_X + i];
#pragma unroll
    for (int off = 32; off > 0; off >>= 1) loc += __shfl_xor(loc, off);
    int lane = tid & 63, wave = tid >> 6;
    if (lane == 0) rnp[wave] = loc;
    __syncthreads();
    if (tid == 0) { int s = rnp[0] + rnp[1] + rnp[2] + rnp[3]; s_np = s; npos[b] = s; }
    __syncthreads();
    long long k = (long long)NEG_POS * s_np;
    if (k > P_ - 1) k = P_ - 1;
    if (k <= 0) { if (tid == 0) sel[b] = -1; return; }

    __shared__ int s_bin;
    __shared__ unsigned s_rem;
    topk_select<NBIN13>(hist + b * NBIN13, (unsigned)k, &s_bin, &s_rem);
    __syncthreads();
    if (tid == 0) { sel[b] = s_bin; remk[b] = (int)s_rem; }
}

// Scan 2: 8-bit histogram (bits 18..11) of in-bin elements.
__global__ __launch_bounds__(1024) void k_hist8(
        const float* __restrict__ ce_neg, const int* __restrict__ sel,
        unsigned* __restrict__ hist8) {
    const int b = blockIdx.y;
    const int s13 = sel[b];
    if (s13 < 0) return;
    const int tid = threadIdx.x;
    __shared__ unsigned h[NBIN8];
    if (tid < NBIN8) h[tid] = 0;
    __syncthreads();
    const float4* v4 = (const float4*)(ce_neg + (size_t)b * P_);
    const int c4 = P_ / SCAN_BLKS / 4;
    const int s4 = blockIdx.x * c4;
    for (int i = s4 + tid; i < s4 + c4; i += 1024) {
        float4 x = v4[i];
        unsigned u0 = __float_as_uint(x.x), u1 = __float_as_uint(x.y);
        unsigned u2 = __float_as_uint(x.z), u3 = __float_as_uint(x.w);
        if ((int)(u0 >> 19) == s13) atomicAdd(&h[(u0 >> 11) & 255u], 1u);
        if ((int)(u1 >> 19) == s13) atomicAdd(&h[(u1 >> 11) & 255u], 1u);
        if ((int)(u2 >> 19) == s13) atomicAdd(&h[(u2 >> 11) & 255u], 1u);
        if ((int)(u3 >> 19) == s13) atomicAdd(&h[(u3 >> 11) & 255u], 1u);
    }
    __syncthreads();
    if (tid < NBIN8 && h[tid]) atomicAdd(&hist8[b * NBIN8 + tid], h[tid]);
}

// Per image: parallel 8-bit select; extend prefix.
__global__ __launch_bounds__(256) void k_sel8(
        const unsigned* __restrict__ hist8, const int* __restrict__ sel,
        unsigned* __restrict__ pref, int* __restrict__ remk) {
    const int b = blockIdx.x;
    if (sel[b] < 0) return;
    __shared__ int s_bin;
    __shared__ unsigned s_rem;
    topk_select<NBIN8>(hist8 + b * NBIN8, (unsigned)remk[b], &s_bin, &s_rem);
    __syncthreads();
    if (threadIdx.x == 0) {
        pref[b] = ((unsigned)sel[b] << 8) | (unsigned)s_bin;   // 21-bit prefix
        remk[b] = (int)s_rem;
    }
}

// Scan 3: 11-bit histogram (bits 10..0) of in-prefix elements.
__global__ __launch_bounds__(1024) void k_hist11(
        const float* __restrict__ ce_neg, const int* __restrict__ sel,
        const unsigned* __restrict__ pref, unsigned* __restrict__ hist11) {
    const int b = blockIdx.y;
    if (sel[b] < 0) return;
    const unsigned pf = pref[b];
    const int tid = threadIdx.x;
    __shared__ unsigned h[NBIN11];
    for (int i = tid; i < NBIN11; i += 1024) h[i] = 0;
    __syncthreads();
    const float4* v4 = (const float4*)(ce_neg + (size_t)b * P_);
    const int c4 = P_ / SCAN_BLKS / 4;
    const int s4 = blockIdx.x * c4;
    for (int i = s4 + tid; i < s4 + c4; i += 1024) {
        float4 x = v4[i];
        unsigned u0 = __float_as_uint(x.x), u1 = __float_as_uint(x.y);
        unsigned u2 = __float_as_uint(x.z), u3 = __float_as_uint(x.w);
        if ((u0 >> 11) == pf) atomicAdd(&h[u0 & 2047u], 1u);
        if ((u1 >> 11) == pf) atomicAdd(&h[u1 & 2047u], 1u);
        if ((u2 >> 11) == pf) atomicAdd(&h[u2 & 2047u], 1u);
        if ((u3 >> 11) == pf) atomicAdd(&h[u3 & 2047u], 1u);
    }
    __syncthreads();
    unsigned* gh = hist11 + b * NBIN11;
    for (int i = tid; i < NBIN11; i += 1024)
        if (h[i]) atomicAdd(&gh[i], h[i]);
}

// Per image: parallel 11-bit select -> final threshold; add rem*T to tot[2].
__global__ __launch_bounds__(256) void k_sel11(
        const unsigned* __restrict__ hist11, const int* __restrict__ sel,
        const unsigned* __restrict__ pref, const int* __restrict__ remk,
        unsigned* __restrict__ thr, double* __restrict__ tot) {
    const int b = blockIdx.x;
    if (sel[b] < 0) { if (threadIdx.x == 0) thr[b] = 0xFFFFFFFFu; return; }
    __shared__ int s_bin;
    __shared__ unsigned s_rem;
    topk_select<NBIN11>(hist11 + b * NBIN11, (unsigned)remk[b], &s_bin, &s_rem);
    __syncthreads();
    if (threadIdx.x == 0) {
        unsigned t = (pref[b] << 11) | (unsigned)s_bin;
        thr[b] = t;
        atomicAdd(&tot[2], (double)s_rem * (double)__uint_as_float(t));  // ties
    }
}

// Scan 4: sum of elements strictly above threshold (double), one atomic/block.
__global__ __launch_bounds__(1024) void k_sumtop(
        const float* __restrict__ ce_neg, const unsigned* __restrict__ thr,
        double* __restrict__ tot) {
    const int b = blockIdx.y;
    const unsigned t = thr[b];
    if (t == 0xFFFFFFFFu) return;
    const int tid = threadIdx.x;
    const float4* v4 = (const float4*)(ce_neg + (size_t)b * P_);
    const int c4 = P_ / SCAN_BLKS / 4;
    const int s4 = blockIdx.x * c4;
    double loc = 0;
    for (int i = s4 + tid; i < s4 + c4; i += 1024) {
        float4 x = v4[i];
        if (__float_as_uint(x.x) > t) loc += x.x;
        if (__float_as_uint(x.y) > t) loc += x.y;
        if (__float_as_uint(x.z) > t) loc += x.z;
        if (__float_as_uint(x.w) > t) loc += x.w;
    }
#pragma unroll
    for (int off = 32; off > 0; off >>= 1) loc += __shfl_xor(loc, off);
    __shared__ double rs[16];
    int lane = tid & 63, wave = tid >> 6;
    if (lane == 0) rs[wave] = loc;
    __syncthreads();
    if (tid == 0) {
        double s = 0;
        for (int w = 0; w < 16; ++w) s += rs[w];
        atomicAdd(&tot[2], s);
    }
}

// Final: reduce k_loss partials (box/landm/pos-ce), add mined tot[2], divide.
__global__ __launch_bounds__(1024) void k_final(
        const double* __restrict__ pb, const double* __restrict__ pl,
        const double* __restrict__ pc, const int* __restrict__ npos,
        const double* __restrict__ tot, float* __restrict__ out) {
    int tid = threadIdx.x;
    double sb = 0, sl = 0, sc = 0;
    for (int i = tid; i < LOSS_BLOCKS; i += 1024) {
        sb += pb[i]; sl += pl[i]; sc += pc[i];
    }
#pragma unroll
    for (int off = 32; off > 0; off >>= 1) {
        sb += __shfl_xor(sb, off);
        sl += __shfl_xor(sl, off);
        sc += __shfl_xor(sc, off);
    }
    __shared__ double rb[16], rl[16], rc[16];
    int lane = tid & 63, wave = tid >> 6;
    if (lane == 0) { rb[wave] = sb; rl[wave] = sl; rc[wave] = sc; }
    __syncthreads();
    if (tid == 0) {
        double b2 = 0, l2 = 0, c2 = 0;
        for (int w = 0; w < 16; ++w) { b2 += rb[w]; l2 += rl[w]; c2 += rc[w]; }
        long long tp = 0;
        for (int b = 0; b < B_; ++b) tp += npos[b];
        double n = tp > 0 ? (double)tp : 1.0;
        out[0] = (float)(b2 / n);             // loss_box
        out[1] = (float)((c2 + tot[2]) / n);  // loss_c (pos part + mined negs)
        out[2] = (float)(l2 / n);             // loss_landm
    }
}

// ---------------- launch ----------------
extern "C" void kernel_launch(void* const* d_in, const int* in_sizes, int n_in,
                              void* d_out, int out_size, void* d_ws, size_t ws_size,
                              hipStream_t stream) {
    const float* conf    = (const float*)d_in[0];
    const float* loc     = (const float*)d_in[1];
    const float* landm   = (const float*)d_in[2];
    const float* priors  = (const float*)d_in[3];
    const float* targets = (const float*)d_in[4];

    char* ws = (char*)d_ws;
    double* tot = (double*)ws;                                   // 4 doubles @0
    int* npos = (int*)(ws + 64);
    int* sel  = (int*)(ws + 128);
    int* remk = (int*)(ws + 192);
    unsigned* pref = (unsigned*)(ws + 256);
    unsigned* thr  = (unsigned*)(ws + 320);
    unsigned long long* pack = (unsigned long long*)(ws + 512);  // 512 u64
    unsigned* hist13 = (unsigned*)(ws + 4608);                   // 512 KB
    unsigned* hist8  = hist13 + (size_t)B_ * NBIN13;             // 16 KB
    unsigned* hist11 = hist8 + (size_t)B_ * NBIN8;               // 128 KB
    size_t zero_bytes = 4608 + (size_t)B_ * (NBIN13 + NBIN8 + NBIN11) * 4;
    size_t big = (zero_bytes + 255) & ~(size_t)255;
    size_t BP = (size_t)B_ * P_;
    float* bt_ov = (float*)(ws + big);
    unsigned char* bt_idx = (unsigned char*)(ws + big + BP * 4);
    float* ce_neg = (float*)(ws + big + BP * 5);
    char* part = ws + big + BP * 9;
    double* pb = (double*)part;
    double* pl = (double*)(part + LOSS_BLOCKS * 8);
    double* pc = (double*)(part + LOSS_BLOCKS * 16);
    int*    pn = (int*)(part + LOSS_BLOCKS * 24);

    // one memset zeroes: tot, npos, sel/remk/pref/thr, pack, all histograms
    hipMemsetAsync(ws, 0, zero_bytes, stream);
    k_match<<<dim3(P_ / (256 * UNR), B_), 256, 0, stream>>>(
        (const float4*)priors, targets, bt_ov, bt_idx, pack);
    k_override<<<1, 64, 0, stream>>>(pack, bt_ov, bt_idx);
    k_loss<<<dim3(LOSS_X, B_), 256, 0, stream>>>(
        (const float2*)conf, (const float4*)loc, landm, (const float4*)priors,
        targets, bt_ov, bt_idx, ce_neg, pb, pl, pc, pn);
    k_hist13<<<dim3(SCAN_BLKS, B_), 1024, 0, stream>>>(ce_neg, hist13);
    k_sel13<<<B_, 256, 0, stream>>>(hist13, pn, sel, remk, npos);
    k_hist8<<<dim3(SCAN_BLKS, B_), 1024, 0, stream>>>(ce_neg, sel, hist8);
    k_sel8<<<B_, 256, 0, stream>>>(hist8, sel, pref, remk);
    k_hist11<<<dim3(SCAN_BLKS, B_), 1024, 0, stream>>>(ce_neg, sel, pref, hist11);
    k_sel11<<<B_, 256, 0, stream>>>(hist11, sel, pref, remk, thr, tot);
    k_sumtop<<<dim3(SCAN_BLKS, B_), 1024, 0, stream>>>(ce_neg, thr, tot);
    k_final<<<1, 1024, 0, stream>>>(pb, pl, pc, npos, tot, (float*)d_out);
}

// Round 8
// 127.377 us; speedup vs baseline: 3.1847x; 1.0050x over previous
//
#include <hip/hip_runtime.h>
#include <math.h>

// Problem constants (from reference)
#define B_ 16
#define P_ 131072
#define G_ 32
constexpr float OVER_THR = 0.35f;
constexpr float VAR0 = 0.1f;
constexpr float VAR1 = 0.2f;
constexpr int NEG_POS = 7;
constexpr int UNR = 8;                         // priors per thread in k_match
constexpr int LOSS_X = P_ / 256;               // 512 blocks per image in k_loss
constexpr int LOSS_BLOCKS = LOSS_X * B_;       // 8192 partials
constexpr int NBIN13 = 8192;                   // 13-bit first-level histogram
constexpr int NBIN8 = 256;                     // second level (bits 18..11)
constexpr int NBIN11 = 2048;                   // third level (bits 10..0)
constexpr int SCAN_BLKS = 16;                  // blocks per image in scans

// ---------------- helpers ----------------
__device__ inline float s1(float d) {            // smooth L1
    d = fabsf(d);
    return d < 1.f ? 0.5f * d * d : d - 0.5f;
}

__device__ inline unsigned long long shfl_xor_u64(unsigned long long x, int m) {
    unsigned lo = (unsigned)x, hi = (unsigned)(x >> 32);
    lo = __shfl_xor(lo, m);
    hi = __shfl_xor(hi, m);
    return ((unsigned long long)hi << 32) | lo;
}

// Block-parallel top-k bin selection (256 threads).
template <int NB>
__device__ void topk_select(const unsigned* __restrict__ h, unsigned rem,
                            int* out_bin, unsigned* out_rem) {
    constexpr int CHUNK = NB / 256;
    const int tid = threadIdx.x;
    unsigned cnt[CHUNK];
    unsigned csum = 0;
#pragma unroll
    for (int j = 0; j < CHUNK; ++j) { cnt[j] = h[tid * CHUNK + j]; csum += cnt[j]; }
    __shared__ unsigned ss[256];
    ss[tid] = csum;
    __syncthreads();
    // Hillis-Steele suffix scan: ss[t] = sum over threads >= t (higher bins)
    for (int off = 1; off < 256; off <<= 1) {
        unsigned other = (tid + off < 256) ? ss[tid + off] : 0u;
        __syncthreads();
        ss[tid] += other;
        __syncthreads();
    }
    unsigned incl = ss[tid];
    unsigned excl = incl - csum;               // strictly above this chunk
    if (excl < rem && incl >= rem) {           // crossing chunk (unique)
        unsigned r = rem - excl, cum = 0;
        int selbin = tid * CHUNK;
#pragma unroll
        for (int j = CHUNK - 1; j >= 0; --j) {
            unsigned c = cnt[j];
            if (cum + c >= r) { selbin = tid * CHUNK + j; r = r - cum; break; }
            cum += c;
        }
        *out_bin = selbin;
        *out_rem = r;
    }
}

// ---------------- kernels ----------------
// Per (b,prior): best truth (first-wins ties) -> bt_ov/bt_idx. Per (b,truth):
// best prior via packed (iou<<32)|~p atomicMax.
// UNR=8 + per-g float tracking + ONE u64 pack+butterfly per g: halves the
// per-prior reduction cost vs round 7 (UNR=4 doubled butterfly count and
// cancelled the occupancy gain — VALU-bound at 80% busy). unroll 1 on the
// g-loop keeps VGPR <~80 (round 3's 256-VGPR blowup was per-pair u64 state
// under full unroll).
__global__ __launch_bounds__(256, 3) void k_match(
        const float4* __restrict__ priors4, const float* __restrict__ targets,
        float* __restrict__ bt_ov, unsigned char* __restrict__ bt_idx,
        unsigned long long* __restrict__ pack) {
    const int b = blockIdx.y;
    const int base = blockIdx.x * (256 * UNR);
    const int tid = threadIdx.x;
    __shared__ float tb[G_][5];                 // x1 y1 x2 y2 area
    __shared__ unsigned long long red[G_][4];
    if (tid < G_ * 4) {
        int g = tid >> 2, j = tid & 3;
        tb[g][j] = targets[((size_t)b * G_ + g) * 15 + j];
    }
    __syncthreads();
    if (tid < G_) tb[tid][4] = (tb[tid][2] - tb[tid][0]) * (tb[tid][3] - tb[tid][1]);
    __syncthreads();

    float px1[UNR], py1[UNR], px2[UNR], py2[UNR], pap[UNR], best[UNR];
    int bidx[UNR];
#pragma unroll
    for (int j = 0; j < UNR; ++j) {
        float4 pr = priors4[base + j * 256 + tid];
        px1[j] = pr.x - pr.z * 0.5f;  py1[j] = pr.y - pr.w * 0.5f;
        px2[j] = pr.x + pr.z * 0.5f;  py2[j] = pr.y + pr.w * 0.5f;
        pap[j] = pr.z * pr.w;
        best[j] = -1.0f; bidx[j] = 0;
    }
    const int lane = tid & 63, wave = tid >> 6;
#pragma unroll 1
    for (int g = 0; g < G_; ++g) {
        float t0 = tb[g][0], t1 = tb[g][1], t2 = tb[g][2], t3 = tb[g][3], ta = tb[g][4];
        float gb = -1.0f; int gj = 0;
#pragma unroll
        for (int j = 0; j < UNR; ++j) {
            float iw = fminf(t2, px2[j]) - fmaxf(t0, px1[j]);
            float ih = fminf(t3, py2[j]) - fmaxf(t1, py1[j]);
            float inter = fmaxf(iw, 0.f) * fmaxf(ih, 0.f);
            float iou = inter * __builtin_amdgcn_rcpf(ta + pap[j] - inter);
            if (iou > best[j]) { best[j] = iou; bidx[j] = g; }  // first-wins ties
            if (iou > gb) { gb = iou; gj = j; }   // first-j wins = lowest p
        }
        // single packed candidate per g: (iou_bits<<32) | ~p  (lowest p on ties)
        unsigned p = (unsigned)(base + (gj << 8) + tid);
        unsigned long long pk =
            ((unsigned long long)__float_as_uint(gb) << 32) | (unsigned)(~p);
#pragma unroll
        for (int off = 32; off > 0; off >>= 1) {
            unsigned long long o = shfl_xor_u64(pk, off);
            if (o > pk) pk = o;
        }
        if (lane == 0) red[g][wave] = pk;
    }
    __syncthreads();
    if (tid < G_) {
        unsigned long long m = red[tid][0];
#pragma unroll
        for (int w = 1; w < 4; ++w) if (red[tid][w] > m) m = red[tid][w];
        atomicMax(&pack[b * G_ + tid], m);
    }
#pragma unroll
    for (int j = 0; j < UNR; ++j) {
        int p = base + j * 256 + tid;
        size_t o = (size_t)b * P_ + p;
        bt_ov[o] = best[j];
        bt_idx[o] = (unsigned char)bidx[j];
    }
}

// Sequential per image: scatter with last-g-wins (numpy semantics).
__global__ void k_override(const unsigned long long* __restrict__ pack,
                           float* __restrict__ bt_ov, unsigned char* __restrict__ bt_idx) {
    int b = threadIdx.x;
    if (b >= B_) return;
    for (int g = 0; g < G_; ++g) {
        unsigned long long pk = pack[b * G_ + g];
        unsigned p = ~(unsigned)(pk & 0xFFFFFFFFull);
        if (p < P_) {
            bt_ov[(size_t)b * P_ + p] = 2.0f;
            bt_idx[(size_t)b * P_ + p] = (unsigned char)g;
        }
    }
}

// Per prior: CE; positives: smooth-L1 on encoded loc/landm. Partials per block.
__global__ __launch_bounds__(256) void k_loss(
        const float2* __restrict__ conf2, const float4* __restrict__ loc4,
        const float* __restrict__ landm, const float4* __restrict__ priors4,
        const float* __restrict__ targets,
        const float* __restrict__ bt_ov, const unsigned char* __restrict__ bt_idx,
        float* __restrict__ ce_neg,
        double* __restrict__ pb, double* __restrict__ pl,
        double* __restrict__ pc, int* __restrict__ pn) {
    const int b = blockIdx.y;
    const int p = blockIdx.x * 256 + threadIdx.x;
    const int tid = threadIdx.x;
    __shared__ float tg[G_ * 15];
    for (int i = tid; i < G_ * 15; i += 256) tg[i] = targets[(size_t)b * G_ * 15 + i];
    __syncthreads();

    const size_t gp = (size_t)b * P_ + p;
    float ov = bt_ov[gp];
    int ti = bt_idx[gp];
    const float* t = &tg[ti * 15];
    float label = t[14];
    int conf_t = (ov < OVER_THR) ? 0 : (int)label;
    bool pos = conf_t > 0;
    int cls = conf_t > 0 ? conf_t : 0;

    float2 c2 = conf2[gp];
    float mx = fmaxf(c2.x, c2.y);
    float lse = mx + logf(expf(c2.x - mx) + expf(c2.y - mx));
    float ce = lse - (cls ? c2.y : c2.x);
    ce_neg[gp] = (!pos && conf_t >= 0) ? ce : 0.f;

    float lb = 0.f, ll = 0.f;
    if (pos) {
        float4 pr = priors4[p];
        float vx = VAR0 * pr.z, vy = VAR0 * pr.w;
        float g0 = ((t[0] + t[2]) * 0.5f - pr.x) / vx;
        float g1 = ((t[1] + t[3]) * 0.5f - pr.y) / vy;
        float g2 = logf((t[2] - t[0]) / pr.z) / VAR1;
        float g3 = logf((t[3] - t[1]) / pr.w) / VAR1;
        float4 ld = loc4[gp];
        lb = s1(ld.x - g0) + s1(ld.y - g1) + s1(ld.z - g2) + s1(ld.w - g3);
        const float* lmp = landm + gp * 10;
#pragma unroll
        for (int i = 0; i < 5; ++i) {
            float2 lm = *(const float2*)(lmp + 2 * i);
            ll += s1(lm.x - (t[4 + 2 * i] - pr.x) / vx)
                + s1(lm.y - (t[5 + 2 * i] - pr.y) / vy);
        }
    }
    double vb = lb, vl = ll, vc = pos ? (double)ce : 0.0;
    int vp = pos ? 1 : 0;
#pragma unroll
    for (int off = 32; off > 0; off >>= 1) {
        vb += __shfl_xor(vb, off);
        vl += __shfl_xor(vl, off);
        vc += __shfl_xor(vc, off);
        vp += __shfl_xor(vp, off);
    }
    __shared__ double rb[4], rl[4], rc[4];
    __shared__ int rp[4];
    int lane = tid & 63, wave = tid >> 6;
    if (lane == 0) { rb[wave] = vb; rl[wave] = vl; rc[wave] = vc; rp[wave] = vp; }
    __syncthreads();
    if (tid == 0) {
        double sb = 0, sl = 0, sc = 0; int sp = 0;
        for (int w = 0; w < 4; ++w) { sb += rb[w]; sl += rl[w]; sc += rc[w]; sp += rp[w]; }
        int bi = blockIdx.y * LOSS_X + blockIdx.x;
        pb[bi] = sb; pl[bi] = sl; pc[bi] = sc; pn[bi] = sp;
    }
}

// Scan 1: 13-bit count histogram of ce_neg float bits, per image. float4 loads.
__global__ __launch_bounds__(1024) void k_hist13(
        const float* __restrict__ ce_neg, unsigned* __restrict__ hist) {
    const int b = blockIdx.y;
    const int tid = threadIdx.x;
    __shared__ unsigned h[NBIN13];
    for (int i = tid; i < NBIN13; i += 1024) h[i] = 0;
    __syncthreads();
    const float4* v4 = (const float4*)(ce_neg + (size_t)b * P_);
    const int c4 = P_ / SCAN_BLKS / 4;
    const int s4 = blockIdx.x * c4;
    for (int i = s4 + tid; i < s4 + c4; i += 1024) {
        float4 x = v4[i];
        atomicAdd(&h[__float_as_uint(x.x) >> 19], 1u);
        atomicAdd(&h[__float_as_uint(x.y) >> 19], 1u);
        atomicAdd(&h[__float_as_uint(x.z) >> 19], 1u);
        atomicAdd(&h[__float_as_uint(x.w) >> 19], 1u);
    }
    __syncthreads();
    unsigned* gh = hist + b * NBIN13;
    for (int i = tid; i < NBIN13; i += 1024)
        if (h[i]) atomicAdd(&gh[i], h[i]);
}

// Per image: sum num_pos from k_loss partials; parallel 13-bit select.
__global__ __launch_bounds__(256) void k_sel13(
        const unsigned* __restrict__ hist, const int* __restrict__ pn,
        int* __restrict__ sel, int* __restrict__ remk, int* __restrict__ npos) {
    const int b = blockIdx.x;
    const int tid = threadIdx.x;
    __shared__ int s_np;
    __shared__ int rnp[4];
    int loc = 0;
    for (int i = tid; i < LOSS_X; i += 256) loc += pn[b * LOSS_X + i];
#pragma unroll
    for (int off = 32; off > 0; off >>= 1) loc += __shfl_xor(loc, off);
    int lane = tid & 63, wave = tid >> 6;
    if (lane == 0) rnp[wave] = loc;
    __syncthreads();
    if (tid == 0) { int s = rnp[0] + rnp[1] + rnp[2] + rnp[3]; s_np = s; npos[b] = s; }
    __syncthreads();
    long long k = (long long)NEG_POS * s_np;
    if (k > P_ - 1) k = P_ - 1;
    if (k <= 0) { if (tid == 0) sel[b] = -1; return; }

    __shared__ int s_bin;
    __shared__ unsigned s_rem;
    topk_select<NBIN13>(hist + b * NBIN13, (unsigned)k, &s_bin, &s_rem);
    __syncthreads();
    if (tid == 0) { sel[b] = s_bin; remk[b] = (int)s_rem; }
}

// Scan 2: 8-bit histogram (bits 18..11) of in-bin elements.
__global__ __launch_bounds__(1024) void k_hist8(
        const float* __restrict__ ce_neg, const int* __restrict__ sel,
        unsigned* __restrict__ hist8) {
    const int b = blockIdx.y;
    const int s13 = sel[b];
    if (s13 < 0) return;
    const int tid = threadIdx.x;
    __shared__ unsigned h[NBIN8];
    if (tid < NBIN8) h[tid] = 0;
    __syncthreads();
    const float4* v4 = (const float4*)(ce_neg + (size_t)b * P_);
    const int c4 = P_ / SCAN_BLKS / 4;
    const int s4 = blockIdx.x * c4;
    for (int i = s4 + tid; i < s4 + c4; i += 1024) {
        float4 x = v4[i];
        unsigned u0 = __float_as_uint(x.x), u1 = __float_as_uint(x.y);
        unsigned u2 = __float_as_uint(x.z), u3 = __float_as_uint(x.w);
        if ((int)(u0 >> 19) == s13) atomicAdd(&h[(u0 >> 11) & 255u], 1u);
        if ((int)(u1 >> 19) == s13) atomicAdd(&h[(u1 >> 11) & 255u], 1u);
        if ((int)(u2 >> 19) == s13) atomicAdd(&h[(u2 >> 11) & 255u], 1u);
        if ((int)(u3 >> 19) == s13) atomicAdd(&h[(u3 >> 11) & 255u], 1u);
    }
    __syncthreads();
    if (tid < NBIN8 && h[tid]) atomicAdd(&hist8[b * NBIN8 + tid], h[tid]);
}

// Per image: parallel 8-bit select; extend prefix.
__global__ __launch_bounds__(256) void k_sel8(
        const unsigned* __restrict__ hist8, const int* __restrict__ sel,
        unsigned* __restrict__ pref, int* __restrict__ remk) {
    const int b = blockIdx.x;
    if (sel[b] < 0) return;
    __shared__ int s_bin;
    __shared__ unsigned s_rem;
    topk_select<NBIN8>(hist8 + b * NBIN8, (unsigned)remk[b], &s_bin, &s_rem);
    __syncthreads();
    if (threadIdx.x == 0) {
        pref[b] = ((unsigned)sel[b] << 8) | (unsigned)s_bin;   // 21-bit prefix
        remk[b] = (int)s_rem;
    }
}

// Scan 3: 11-bit histogram (bits 10..0) of in-prefix elements.
__global__ __launch_bounds__(1024) void k_hist11(
        const float* __restrict__ ce_neg, const int* __restrict__ sel,
        const unsigned* __restrict__ pref, unsigned* __restrict__ hist11) {
    const int b = blockIdx.y;
    if (sel[b] < 0) return;
    const unsigned pf = pref[b];
    const int tid = threadIdx.x;
    __shared__ unsigned h[NBIN11];
    for (int i = tid; i < NBIN11; i += 1024) h[i] = 0;
    __syncthreads();
    const float4* v4 = (const float4*)(ce_neg + (size_t)b * P_);
    const int c4 = P_ / SCAN_BLKS / 4;
    const int s4 = blockIdx.x * c4;
    for (int i = s4 + tid; i < s4 + c4; i += 1024) {
        float4 x = v4[i];
        unsigned u0 = __float_as_uint(x.x), u1 = __float_as_uint(x.y);
        unsigned u2 = __float_as_uint(x.z), u3 = __float_as_uint(x.w);
        if ((u0 >> 11) == pf) atomicAdd(&h[u0 & 2047u], 1u);
        if ((u1 >> 11) == pf) atomicAdd(&h[u1 & 2047u], 1u);
        if ((u2 >> 11) == pf) atomicAdd(&h[u2 & 2047u], 1u);
        if ((u3 >> 11) == pf) atomicAdd(&h[u3 & 2047u], 1u);
    }
    __syncthreads();
    unsigned* gh = hist11 + b * NBIN11;
    for (int i = tid; i < NBIN11; i += 1024)
        if (h[i]) atomicAdd(&gh[i], h[i]);
}

// Per image: parallel 11-bit select -> final threshold; add rem*T to tot[2].
__global__ __launch_bounds__(256) void k_sel11(
        const unsigned* __restrict__ hist11, const int* __restrict__ sel,
        const unsigned* __restrict__ pref, const int* __restrict__ remk,
        unsigned* __restrict__ thr, double* __restrict__ tot) {
    const int b = blockIdx.x;
    if (sel[b] < 0) { if (threadIdx.x == 0) thr[b] = 0xFFFFFFFFu; return; }
    __shared__ int s_bin;
    __shared__ unsigned s_rem;
    topk_select<NBIN11>(hist11 + b * NBIN11, (unsigned)remk[b], &s_bin, &s_rem);
    __syncthreads();
    if (threadIdx.x == 0) {
        unsigned t = (pref[b] << 11) | (unsigned)s_bin;
        thr[b] = t;
        atomicAdd(&tot[2], (double)s_rem * (double)__uint_as_float(t));  // ties
    }
}

// Scan 4: sum of elements strictly above threshold (double), one atomic/block.
__global__ __launch_bounds__(1024) void k_sumtop(
        const float* __restrict__ ce_neg, const unsigned* __restrict__ thr,
        double* __restrict__ tot) {
    const int b = blockIdx.y;
    const unsigned t = thr[b];
    if (t == 0xFFFFFFFFu) return;
    const int tid = threadIdx.x;
    const float4* v4 = (const float4*)(ce_neg + (size_t)b * P_);
    const int c4 = P_ / SCAN_BLKS / 4;
    const int s4 = blockIdx.x * c4;
    double loc = 0;
    for (int i = s4 + tid; i < s4 + c4; i += 1024) {
        float4 x = v4[i];
        if (__float_as_uint(x.x) > t) loc += x.x;
        if (__float_as_uint(x.y) > t) loc += x.y;
        if (__float_as_uint(x.z) > t) loc += x.z;
        if (__float_as_uint(x.w) > t) loc += x.w;
    }
#pragma unroll
    for (int off = 32; off > 0; off >>= 1) loc += __shfl_xor(loc, off);
    __shared__ double rs[16];
    int lane = tid & 63, wave = tid >> 6;
    if (lane == 0) rs[wave] = loc;
    __syncthreads();
    if (tid == 0) {
        double s = 0;
        for (int w = 0; w < 16; ++w) s += rs[w];
        atomicAdd(&tot[2], s);
    }
}

// Final: reduce k_loss partials (box/landm/pos-ce), add mined tot[2], divide.
__global__ __launch_bounds__(1024) void k_final(
        const double* __restrict__ pb, const double* __restrict__ pl,
        const double* __restrict__ pc, const int* __restrict__ npos,
        const double* __restrict__ tot, float* __restrict__ out) {
    int tid = threadIdx.x;
    double sb = 0, sl = 0, sc = 0;
    for (int i = tid; i < LOSS_BLOCKS; i += 1024) {
        sb += pb[i]; sl += pl[i]; sc += pc[i];
    }
#pragma unroll
    for (int off = 32; off > 0; off >>= 1) {
        sb += __shfl_xor(sb, off);
        sl += __shfl_xor(sl, off);
        sc += __shfl_xor(sc, off);
    }
    __shared__ double rb[16], rl[16], rc[16];
    int lane = tid & 63, wave = tid >> 6;
    if (lane == 0) { rb[wave] = sb; rl[wave] = sl; rc[wave] = sc; }
    __syncthreads();
    if (tid == 0) {
        double b2 = 0, l2 = 0, c2 = 0;
        for (int w = 0; w < 16; ++w) { b2 += rb[w]; l2 += rl[w]; c2 += rc[w]; }
        long long tp = 0;
        for (int b = 0; b < B_; ++b) tp += npos[b];
        double n = tp > 0 ? (double)tp : 1.0;
        out[0] = (float)(b2 / n);             // loss_box
        out[1] = (float)((c2 + tot[2]) / n);  // loss_c (pos part + mined negs)
        out[2] = (float)(l2 / n);             // loss_landm
    }
}

// ---------------- launch ----------------
extern "C" void kernel_launch(void* const* d_in, const int* in_sizes, int n_in,
                              void* d_out, int out_size, void* d_ws, size_t ws_size,
                              hipStream_t stream) {
    const float* conf    = (const float*)d_in[0];
    const float* loc     = (const float*)d_in[1];
    const float* landm   = (const float*)d_in[2];
    const float* priors  = (const float*)d_in[3];
    const float* targets = (const float*)d_in[4];

    char* ws = (char*)d_ws;
    double* tot = (double*)ws;                                   // 4 doubles @0
    int* npos = (int*)(ws + 64);
    int* sel  = (int*)(ws + 128);
    int* remk = (int*)(ws + 192);
    unsigned* pref = (unsigned*)(ws + 256);
    unsigned* thr  = (unsigned*)(ws + 320);
    unsigned long long* pack = (unsigned long long*)(ws + 512);  // 512 u64
    unsigned* hist13 = (unsigned*)(ws + 4608);                   // 512 KB
    unsigned* hist8  = hist13 + (size_t)B_ * NBIN13;             // 16 KB
    unsigned* hist11 = hist8 + (size_t)B_ * NBIN8;               // 128 KB
    size_t zero_bytes = 4608 + (size_t)B_ * (NBIN13 + NBIN8 + NBIN11) * 4;
    size_t big = (zero_bytes + 255) & ~(size_t)255;
    size_t BP = (size_t)B_ * P_;
    float* bt_ov = (float*)(ws + big);
    unsigned char* bt_idx = (unsigned char*)(ws + big + BP * 4);
    float* ce_neg = (float*)(ws + big + BP * 5);
    char* part = ws + big + BP * 9;
    double* pb = (double*)part;
    double* pl = (double*)(part + LOSS_BLOCKS * 8);
    double* pc = (double*)(part + LOSS_BLOCKS * 16);
    int*    pn = (int*)(part + LOSS_BLOCKS * 24);

    // one memset zeroes: tot, npos, sel/remk/pref/thr, pack, all histograms
    hipMemsetAsync(ws, 0, zero_bytes, stream);
    k_match<<<dim3(P_ / (256 * UNR), B_), 256, 0, stream>>>(
        (const float4*)priors, targets, bt_ov, bt_idx, pack);
    k_override<<<1, 64, 0, stream>>>(pack, bt_ov, bt_idx);
    k_loss<<<dim3(LOSS_X, B_), 256, 0, stream>>>(
        (const float2*)conf, (const float4*)loc, landm, (const float4*)priors,
        targets, bt_ov, bt_idx, ce_neg, pb, pl, pc, pn);
    k_hist13<<<dim3(SCAN_BLKS, B_), 1024, 0, stream>>>(ce_neg, hist13);
    k_sel13<<<B_, 256, 0, stream>>>(hist13, pn, sel, remk, npos);
    k_hist8<<<dim3(SCAN_BLKS, B_), 1024, 0, stream>>>(ce_neg, sel, hist8);
    k_sel8<<<B_, 256, 0, stream>>>(hist8, sel, pref, remk);
    k_hist11<<<dim3(SCAN_BLKS, B_), 1024, 0, stream>>>(ce_neg, sel, pref, hist11);
    k_sel11<<<B_, 256, 0, stream>>>(hist11, sel, pref, remk, thr, tot);
    k_sumtop<<<dim3(SCAN_BLKS, B_), 1024, 0, stream>>>(ce_neg, thr, tot);
    k_final<<<1, 1024, 0, stream>>>(pb, pl, pc, npos, tot, (float*)d_out);
}